// Round 7
// baseline (174.459 us; speedup 1.0000x reference)
//
#include <hip/hip_runtime.h>
#include <math.h>

#define Bc 4
#define Vc 4
#define Hc 256
#define Wc 384
#define HWc (Hc*Wc)               // 98304
#define TOTc (Bc*Vc*HWc)          // 1572864
#define SCALE_MIN_c 1e-05f
#define SCALE_MAX_c 30.0f
#define EPS_c 1e-08f

// Output section offsets (in floats)
#define MEANS_OFF  ((size_t)0)
#define SCALES_OFF ((size_t)TOTc*3)
#define ROT_OFF    ((size_t)TOTc*6)
#define HARM_OFF   ((size_t)TOTc*10)
#define OPAC_OFF   ((size_t)TOTc*13)

// PERSISTENT + PIPELINED version of the (passing) round-6 kernel:
//   - grid = 768 blocks = exactly 3 resident blocks/CU (one round, no turnover)
//   - each block processes 2 consecutive 1024-px tiles; tile-B's 20 loads are
//     issued BEFORE tile-A's compute, so the memory pipe stays busy during
//     A's compute/LDS/store phase (attacks the measured ~25us fixed component)
//   - per-tile processing identical to round 6 (strided lane ownership, dense
//     f4 stores via single-use-per-phase LDS repack, write/barrier/read).
// Tile pairs (2b, 2b+1) never straddle a view boundary (96 even, pairs even+odd).
__global__ __launch_bounds__(256, 3) void ga_kernel(
    const float* __restrict__ ext,    // (B,V,4,4)
    const float* __restrict__ intr,   // (B,V,3,3)
    const float* __restrict__ depths, // (B,V,H,W)
    const float* __restrict__ opac,   // (B,V,H,W)
    const float* __restrict__ raw,    // (B,V,H,W,12)
    float* __restrict__ out)
{
    __shared__ float sM[4][768];      // 12 KB means   (wave-private rows)
    __shared__ float sS[4][768];      // 12 KB scales
    __shared__ float sH[4][768];      // 12 KB harmonics

    const int tid  = threadIdx.x;
    const int lane = tid & 63;
    const int wv   = tid >> 6;
    const int tA   = blockIdx.x * 2;                 // first tile of this block
    const int bview = tA / 96;                       // same view for both tiles
    const int waveBaseA = tA * 1024 + wv * 256;      // global pixel base, tile A
    const int waveBaseB = waveBaseA + 1024;          // tile B
    const int pvBaseA   = (tA - bview * 96) * 1024 + wv * 256;  // within-view
    const int pvBaseB   = pvBaseA + 1024;
    float* sMw = sM[wv];
    float* sSw = sS[wv];
    float* sHw = sH[wv];

    const int li = 3 * lane;

    // ---- issue tile-A loads, then tile-B loads: 40 VMEM ops in flight ----
    const float4* r4A = reinterpret_cast<const float4*>(raw) + (size_t)waveBaseA * 3;
    const float4* r4B = reinterpret_cast<const float4*>(raw) + (size_t)waveBaseB * 3;

    float4 va[12], vb[12];
    float  da[4], pa[4], db[4], pb[4];
    #pragma unroll
    for (int k = 0; k < 4; ++k) {
        va[3*k+0] = r4A[192*k + li + 0];
        va[3*k+1] = r4A[192*k + li + 1];
        va[3*k+2] = r4A[192*k + li + 2];
    }
    #pragma unroll
    for (int k = 0; k < 4; ++k) {
        da[k] = depths[waveBaseA + 64*k + lane];
        pa[k] = opac  [waveBaseA + 64*k + lane];
    }
    #pragma unroll
    for (int k = 0; k < 4; ++k) {
        vb[3*k+0] = r4B[192*k + li + 0];
        vb[3*k+1] = r4B[192*k + li + 1];
        vb[3*k+2] = r4B[192*k + li + 2];
    }
    #pragma unroll
    for (int k = 0; k < 4; ++k) {
        db[k] = depths[waveBaseB + 64*k + lane];
        pb[k] = opac  [waveBaseB + 64*k + lane];
    }

    // ---- per-view constants (computed once; shared by both tiles) ----
    const float* E = ext  + bview * 16;
    const float* I = intr + bview * 9;

    const float R0 = E[0], R1 = E[4], R2 = E[8];
    const float R3 = E[1], R4 = E[5], R5 = E[9];
    const float R6 = E[2], R7 = E[6], R8 = E[10];
    const float t0 = E[3], t1 = E[7], t2 = E[11];
    const float O0 = -(R0*t0 + R1*t1 + R2*t2);
    const float O1 = -(R3*t0 + R4*t1 + R5*t2);
    const float O2 = -(R6*t0 + R7*t1 + R8*t2);

    const float a00 = I[0]*(1.0f/Wc), a01 = I[1]*(1.0f/Wc), a02 = I[2]*(1.0f/Wc);
    const float a10 = I[3]*(1.0f/Hc), a11 = I[4]*(1.0f/Hc), a12 = I[5]*(1.0f/Hc);
    const float a20 = I[6],           a21 = I[7],           a22 = I[8];
    const float det = a00*(a11*a22 - a12*a21)
                    - a01*(a10*a22 - a12*a20)
                    + a02*(a10*a21 - a11*a20);
    const float id = 1.0f / det;
    const float K0 = (a11*a22 - a12*a21)*id;
    const float K1 = (a02*a21 - a01*a22)*id;
    const float K2 = (a01*a12 - a02*a11)*id;
    const float K3 = (a12*a20 - a10*a22)*id;
    const float K4 = (a00*a22 - a02*a20)*id;
    const float K5 = (a02*a10 - a00*a12)*id;
    const float K6 = (a10*a21 - a11*a20)*id;
    const float K7 = (a01*a20 - a00*a21)*id;
    const float K8 = (a00*a11 - a01*a10)*id;

    const float det2 = a00*a11 - a01*a10;
    const float mult = 0.1f * ((a11*(1.0f/Wc) - a01*(1.0f/Hc))
                             + (-a10*(1.0f/Wc) + a00*(1.0f/Hc))) / det2;

    const float qa0 = sqrtf(fmaxf(0.0f, 1.0f + R0 + R4 + R8));
    const float qa1 = sqrtf(fmaxf(0.0f, 1.0f + R0 - R4 - R8));
    const float qa2 = sqrtf(fmaxf(0.0f, 1.0f - R0 + R4 - R8));
    const float qa3 = sqrtf(fmaxf(0.0f, 1.0f - R0 - R4 + R8));
    float bq = qa0;
    float b0 = qa0*qa0, b1 = R7 - R5, b2 = R2 - R6, b3 = R3 - R1;
    {
        const bool s1 = qa1 > bq;
        b0 = s1 ? (R7 - R5)   : b0;
        b1 = s1 ? (qa1*qa1)   : b1;
        b2 = s1 ? (R3 + R1)   : b2;
        b3 = s1 ? (R2 + R6)   : b3;
        bq = s1 ? qa1 : bq;
        const bool s2 = qa2 > bq;
        b0 = s2 ? (R2 - R6)   : b0;
        b1 = s2 ? (R3 + R1)   : b1;
        b2 = s2 ? (qa2*qa2)   : b2;
        b3 = s2 ? (R5 + R7)   : b3;
        bq = s2 ? qa2 : bq;
        const bool s3 = qa3 > bq;
        b0 = s3 ? (R3 - R1)   : b0;
        b1 = s3 ? (R6 + R2)   : b1;
        b2 = s3 ? (R7 + R5)   : b2;
        b3 = s3 ? (qa3*qa3)   : b3;
        bq = s3 ? qa3 : bq;
    }
    const float dd = 1.0f / (2.0f * fmaxf(bq, 0.1f));
    const float q0 = b0*dd, q1 = b1*dd, q2 = b2*dd, q3 = b3*dd;
    const float qn = 1.0f / sqrtf(q0*q0 + q1*q1 + q2*q2 + q3*q3);
    const float aw = q0*qn, ax = q1*qn, ay = q2*qn, az = q3*qn;

    // ---- per-pixel body (identical to round 6; p is WITHIN-VIEW index) ----
    auto PIX = [&](const float4 A, const float4 Bq, const float4 C,
                   const float dep, const int p, const int sbase) -> float4 {
        const int h = p / Wc;
        const int w = p - h * Wc;
        const float x = (w + 0.5f) * (1.0f/Wc) + A.x * (1.0f/Wc);
        const float y = (h + 0.5f) * (1.0f/Hc) + A.y * (1.0f/Hc);

        float dc0 = K0*x + K1*y + K2;
        float dc1 = K3*x + K4*y + K5;
        float dc2 = K6*x + K7*y + K8;
        const float inl = rsqrtf(dc0*dc0 + dc1*dc1 + dc2*dc2);
        dc0 *= inl; dc1 *= inl; dc2 *= inl;

        const float dw0 = R0*dc0 + R1*dc1 + R2*dc2;
        const float dw1 = R3*dc0 + R4*dc1 + R5*dc2;
        const float dw2 = R6*dc0 + R7*dc1 + R8*dc2;

        sMw[sbase+0] = O0 + dw0*dep;
        sMw[sbase+1] = O1 + dw1*dep;
        sMw[sbase+2] = O2 + dw2*dep;

        const float sm = dep * mult;
        sSw[sbase+0] = (SCALE_MIN_c + (SCALE_MAX_c - SCALE_MIN_c) / (1.0f + __expf(-A.z))) * sm;
        sSw[sbase+1] = (SCALE_MIN_c + (SCALE_MAX_c - SCALE_MIN_c) / (1.0f + __expf(-A.w))) * sm;
        sSw[sbase+2] = (SCALE_MIN_c + (SCALE_MAX_c - SCALE_MIN_c) / (1.0f + __expf(-Bq.x))) * sm;

        sHw[sbase+0] = C.y;   // raw[9:12] passthrough
        sHw[sbase+1] = C.z;
        sHw[sbase+2] = C.w;

        const float rx = Bq.y, ry = Bq.z, rz = Bq.w, rw = C.x;
        const float rn = 1.0f / (sqrtf(rx*rx + ry*ry + rz*rz + rw*rw) + EPS_c);
        const float bwq = rw*rn, bxq = rx*rn, byq = ry*rn, bzq = rz*rn;
        float4 wq;
        wq.x = aw*bwq - ax*bxq - ay*byq - az*bzq;
        wq.y = aw*bxq + ax*bwq + ay*bzq - az*byq;
        wq.z = aw*byq - ax*bzq + ay*bwq + az*bxq;
        wq.w = aw*bzq + ax*byq - ay*bxq + az*bwq;
        return wq;
    };

    float4* outR4 = reinterpret_cast<float4*>(out + ROT_OFF);

    // ================= tile A: compute -> LDS, rot/opac direct =================
    #pragma unroll
    for (int k = 0; k < 4; ++k) {
        outR4[waveBaseA + 64*k + lane] =
            PIX(va[3*k], va[3*k+1], va[3*k+2], da[k],
                pvBaseA + 64*k + lane, (64*k + lane)*3);
        out[OPAC_OFF + waveBaseA + 64*k + lane] = pa[k];
    }

    __syncthreads();   // A: LDS writes -> reads

    {
        const float4* svM = reinterpret_cast<const float4*>(sMw);
        const float4* svS = reinterpret_cast<const float4*>(sSw);
        const float4* svH = reinterpret_cast<const float4*>(sHw);
        float4* oM = reinterpret_cast<float4*>(out + MEANS_OFF  + (size_t)waveBaseA * 3);
        float4* oS = reinterpret_cast<float4*>(out + SCALES_OFF + (size_t)waveBaseA * 3);
        float4* oH = reinterpret_cast<float4*>(out + HARM_OFF   + (size_t)waveBaseA * 3);
        #pragma unroll
        for (int k = 0; k < 3; ++k) {
            oM[64*k + lane] = svM[64*k + lane];
            oS[64*k + lane] = svS[64*k + lane];
            oH[64*k + lane] = svH[64*k + lane];
        }
    }

    __syncthreads();   // A reads done before B overwrites LDS

    // ================= tile B: compute -> LDS, rot/opac direct =================
    #pragma unroll
    for (int k = 0; k < 4; ++k) {
        outR4[waveBaseB + 64*k + lane] =
            PIX(vb[3*k], vb[3*k+1], vb[3*k+2], db[k],
                pvBaseB + 64*k + lane, (64*k + lane)*3);
        out[OPAC_OFF + waveBaseB + 64*k + lane] = pb[k];
    }

    __syncthreads();   // B: LDS writes -> reads

    {
        const float4* svM = reinterpret_cast<const float4*>(sMw);
        const float4* svS = reinterpret_cast<const float4*>(sSw);
        const float4* svH = reinterpret_cast<const float4*>(sHw);
        float4* oM = reinterpret_cast<float4*>(out + MEANS_OFF  + (size_t)waveBaseB * 3);
        float4* oS = reinterpret_cast<float4*>(out + SCALES_OFF + (size_t)waveBaseB * 3);
        float4* oH = reinterpret_cast<float4*>(out + HARM_OFF   + (size_t)waveBaseB * 3);
        #pragma unroll
        for (int k = 0; k < 3; ++k) {
            oM[64*k + lane] = svM[64*k + lane];
            oS[64*k + lane] = svS[64*k + lane];
            oH[64*k + lane] = svH[64*k + lane];
        }
    }
}

extern "C" void kernel_launch(void* const* d_in, const int* in_sizes, int n_in,
                              void* d_out, int out_size, void* d_ws, size_t ws_size,
                              hipStream_t stream) {
    const float* ext    = (const float*)d_in[0];
    const float* intr   = (const float*)d_in[1];
    const float* depths = (const float*)d_in[2];
    const float* opac   = (const float*)d_in[3];
    const float* raw    = (const float*)d_in[4];
    float* out = (float*)d_out;

    ga_kernel<<<TOTc / 2048, 256, 0, stream>>>(ext, intr, depths, opac, raw, out);
}

// Round 9
// 173.605 us; speedup vs baseline: 1.0049x; 1.0049x over previous
//
#include <hip/hip_runtime.h>
#include <math.h>

#define Bc 4
#define Vc 4
#define Hc 256
#define Wc 384
#define HWc (Hc*Wc)               // 98304
#define TOTc (Bc*Vc*HWc)          // 1572864
#define SCALE_MIN_c 1e-05f
#define SCALE_MAX_c 30.0f
#define EPS_c 1e-08f

// Output section offsets (in floats)
#define MEANS_OFF  ((size_t)0)
#define SCALES_OFF ((size_t)TOTc*3)
#define ROT_OFF    ((size_t)TOTc*6)
#define HARM_OFF   ((size_t)TOTc*10)
#define OPAC_OFF   ((size_t)TOTc*13)

// clang-native 4-float vector: __builtin_nontemporal_store accepts this
// (it rejects HIP_vector_type<float,4>, which is a struct). Same 16B layout.
typedef float vf4 __attribute__((ext_vector_type(4)));

__device__ __forceinline__ void nt_store4(const float4 v, float4* p) {
    vf4 x; x.x = v.x; x.y = v.y; x.z = v.z; x.w = v.w;
    __builtin_nontemporal_store(x, reinterpret_cast<vf4*>(p));
}

// Round-6 structure (best passing: 54.0us/dispatch) with ONE change:
// all output stores are NON-TEMPORAL (nt flag). Mechanism under test:
// cached stores write-allocate 86MB into L2/L3 each dispatch, evicting
// ~half the 81MB input (FETCH_SIZE == 44MB == input/2 across R0/R1/R6).
// nt stores stream to HBM without allocation -> input stays L3-resident,
// reads become L3-hits, writes ride the fill-kernel path (6.7 TB/s).
__global__ __launch_bounds__(256, 4) void ga_kernel(
    const float* __restrict__ ext,    // (B,V,4,4)
    const float* __restrict__ intr,   // (B,V,3,3)
    const float* __restrict__ depths, // (B,V,H,W)
    const float* __restrict__ opac,   // (B,V,H,W)
    const float* __restrict__ raw,    // (B,V,H,W,12)
    float* __restrict__ out)
{
    __shared__ float sM[4][768];      // 12 KB means   (wave-private rows)
    __shared__ float sS[4][768];      // 12 KB scales
    __shared__ float sH[4][768];      // 12 KB harmonics

    const int tid  = threadIdx.x;
    const int lane = tid & 63;
    const int wv   = tid >> 6;
    const int waveBase = blockIdx.x * 1024 + wv * 256;        // global pixel base
    const int bview    = blockIdx.x / 96;                     // 96 blocks per view
    const int pvBase   = (blockIdx.x - bview * 96) * 1024 + wv * 256; // within-view
    float* sMw = sM[wv];
    float* sSw = sS[wv];
    float* sHw = sH[wv];

    // ---- issue ALL 20 independent loads up front ----
    const float4* r4 = reinterpret_cast<const float4*>(raw) + (size_t)waveBase * 3;
    const int li = 3 * lane;
    const float4 v0 = r4[      li+0], v1 = r4[      li+1], v2 = r4[      li+2];
    const float  d0 = depths[waveBase       + lane];
    const float  p0 = opac  [waveBase       + lane];
    const float4 v3 = r4[192 + li+0], v4 = r4[192 + li+1], v5 = r4[192 + li+2];
    const float  d1 = depths[waveBase +  64 + lane];
    const float  p1 = opac  [waveBase +  64 + lane];
    const float4 v6 = r4[384 + li+0], v7 = r4[384 + li+1], v8 = r4[384 + li+2];
    const float  d2 = depths[waveBase + 128 + lane];
    const float  p2 = opac  [waveBase + 128 + lane];
    const float4 v9 = r4[576 + li+0], v10= r4[576 + li+1], v11= r4[576 + li+2];
    const float  d3 = depths[waveBase + 192 + lane];
    const float  p3 = opac  [waveBase + 192 + lane];

    // ---- per-view constants (uniform s_loads; computed once per thread) ----
    const float* E = ext  + bview * 16;
    const float* I = intr + bview * 9;

    const float R0 = E[0], R1 = E[4], R2 = E[8];
    const float R3 = E[1], R4 = E[5], R5 = E[9];
    const float R6 = E[2], R7 = E[6], R8 = E[10];
    const float t0 = E[3], t1 = E[7], t2 = E[11];
    const float O0 = -(R0*t0 + R1*t1 + R2*t2);
    const float O1 = -(R3*t0 + R4*t1 + R5*t2);
    const float O2 = -(R6*t0 + R7*t1 + R8*t2);

    const float a00 = I[0]*(1.0f/Wc), a01 = I[1]*(1.0f/Wc), a02 = I[2]*(1.0f/Wc);
    const float a10 = I[3]*(1.0f/Hc), a11 = I[4]*(1.0f/Hc), a12 = I[5]*(1.0f/Hc);
    const float a20 = I[6],           a21 = I[7],           a22 = I[8];
    const float det = a00*(a11*a22 - a12*a21)
                    - a01*(a10*a22 - a12*a20)
                    + a02*(a10*a21 - a11*a20);
    const float id = 1.0f / det;
    const float K0 = (a11*a22 - a12*a21)*id;
    const float K1 = (a02*a21 - a01*a22)*id;
    const float K2 = (a01*a12 - a02*a11)*id;
    const float K3 = (a12*a20 - a10*a22)*id;
    const float K4 = (a00*a22 - a02*a20)*id;
    const float K5 = (a02*a10 - a00*a12)*id;
    const float K6 = (a10*a21 - a11*a20)*id;
    const float K7 = (a01*a20 - a00*a21)*id;
    const float K8 = (a00*a11 - a01*a10)*id;

    const float det2 = a00*a11 - a01*a10;
    const float mult = 0.1f * ((a11*(1.0f/Wc) - a01*(1.0f/Hc))
                             + (-a10*(1.0f/Wc) + a00*(1.0f/Hc))) / det2;

    const float qa0 = sqrtf(fmaxf(0.0f, 1.0f + R0 + R4 + R8));
    const float qa1 = sqrtf(fmaxf(0.0f, 1.0f + R0 - R4 - R8));
    const float qa2 = sqrtf(fmaxf(0.0f, 1.0f - R0 + R4 - R8));
    const float qa3 = sqrtf(fmaxf(0.0f, 1.0f - R0 - R4 + R8));
    float bq = qa0;
    float b0 = qa0*qa0, b1 = R7 - R5, b2 = R2 - R6, b3 = R3 - R1;
    {
        const bool s1 = qa1 > bq;
        b0 = s1 ? (R7 - R5)   : b0;
        b1 = s1 ? (qa1*qa1)   : b1;
        b2 = s1 ? (R3 + R1)   : b2;
        b3 = s1 ? (R2 + R6)   : b3;
        bq = s1 ? qa1 : bq;
        const bool s2 = qa2 > bq;
        b0 = s2 ? (R2 - R6)   : b0;
        b1 = s2 ? (R3 + R1)   : b1;
        b2 = s2 ? (qa2*qa2)   : b2;
        b3 = s2 ? (R5 + R7)   : b3;
        bq = s2 ? qa2 : bq;
        const bool s3 = qa3 > bq;
        b0 = s3 ? (R3 - R1)   : b0;
        b1 = s3 ? (R6 + R2)   : b1;
        b2 = s3 ? (R7 + R5)   : b2;
        b3 = s3 ? (qa3*qa3)   : b3;
        bq = s3 ? qa3 : bq;
    }
    const float dd = 1.0f / (2.0f * fmaxf(bq, 0.1f));
    const float q0 = b0*dd, q1 = b1*dd, q2 = b2*dd, q3 = b3*dd;
    const float qn = 1.0f / sqrtf(q0*q0 + q1*q1 + q2*q2 + q3*q3);
    const float aw = q0*qn, ax = q1*qn, ay = q2*qn, az = q3*qn;

    // ---- per-pixel body: rot returned (nt-stored dense from registers);
    //      means/scales/harm written ONCE into this wave's LDS rows.
    //      p is the WITHIN-VIEW pixel index (geometry only). ----
    auto PIX = [&](const float4 A, const float4 Bq, const float4 C,
                   const float dep, const int p, const int sbase) -> float4 {
        const int h = p / Wc;
        const int w = p - h * Wc;
        const float x = (w + 0.5f) * (1.0f/Wc) + A.x * (1.0f/Wc);
        const float y = (h + 0.5f) * (1.0f/Hc) + A.y * (1.0f/Hc);

        float dc0 = K0*x + K1*y + K2;
        float dc1 = K3*x + K4*y + K5;
        float dc2 = K6*x + K7*y + K8;
        const float inl = rsqrtf(dc0*dc0 + dc1*dc1 + dc2*dc2);
        dc0 *= inl; dc1 *= inl; dc2 *= inl;

        const float dw0 = R0*dc0 + R1*dc1 + R2*dc2;
        const float dw1 = R3*dc0 + R4*dc1 + R5*dc2;
        const float dw2 = R6*dc0 + R7*dc1 + R8*dc2;

        sMw[sbase+0] = O0 + dw0*dep;
        sMw[sbase+1] = O1 + dw1*dep;
        sMw[sbase+2] = O2 + dw2*dep;

        const float sm = dep * mult;
        sSw[sbase+0] = (SCALE_MIN_c + (SCALE_MAX_c - SCALE_MIN_c) / (1.0f + __expf(-A.z))) * sm;
        sSw[sbase+1] = (SCALE_MIN_c + (SCALE_MAX_c - SCALE_MIN_c) / (1.0f + __expf(-A.w))) * sm;
        sSw[sbase+2] = (SCALE_MIN_c + (SCALE_MAX_c - SCALE_MIN_c) / (1.0f + __expf(-Bq.x))) * sm;

        sHw[sbase+0] = C.y;   // raw[9:12] passthrough
        sHw[sbase+1] = C.z;
        sHw[sbase+2] = C.w;

        const float rx = Bq.y, ry = Bq.z, rz = Bq.w, rw = C.x;
        const float rn = 1.0f / (sqrtf(rx*rx + ry*ry + rz*rz + rw*rw) + EPS_c);
        const float bwq = rw*rn, bxq = rx*rn, byq = ry*rn, bzq = rz*rn;
        float4 wq;
        wq.x = aw*bwq - ax*bxq - ay*byq - az*bzq;
        wq.y = aw*bxq + ax*bwq + ay*bzq - az*byq;
        wq.z = aw*byq - ax*bzq + ay*bwq + az*bxq;
        wq.w = aw*bzq + ax*byq - ay*bxq + az*bwq;
        return wq;
    };

    float4* outR4 = reinterpret_cast<float4*>(out + ROT_OFF);

    nt_store4(PIX(v0, v1, v2,  d0, pvBase       + lane, (      lane)*3),
              &outR4[waveBase       + lane]);
    __builtin_nontemporal_store(p0, &out[OPAC_OFF + waveBase       + lane]);
    nt_store4(PIX(v3, v4, v5,  d1, pvBase +  64 + lane, ( 64 + lane)*3),
              &outR4[waveBase +  64 + lane]);
    __builtin_nontemporal_store(p1, &out[OPAC_OFF + waveBase +  64 + lane]);
    nt_store4(PIX(v6, v7, v8,  d2, pvBase + 128 + lane, (128 + lane)*3),
              &outR4[waveBase + 128 + lane]);
    __builtin_nontemporal_store(p2, &out[OPAC_OFF + waveBase + 128 + lane]);
    nt_store4(PIX(v9, v10,v11, d3, pvBase + 192 + lane, (192 + lane)*3),
              &outR4[waveBase + 192 + lane]);
    __builtin_nontemporal_store(p3, &out[OPAC_OFF + waveBase + 192 + lane]);

    // ---- write/BARRIER/read: bulletproof ordering for the repack ----
    __syncthreads();

    {
        const float4* sv = reinterpret_cast<const float4*>(sMw);
        float4* o = reinterpret_cast<float4*>(out + MEANS_OFF + (size_t)waveBase * 3);
        nt_store4(sv[      lane], &o[      lane]);
        nt_store4(sv[ 64 + lane], &o[ 64 + lane]);
        nt_store4(sv[128 + lane], &o[128 + lane]);
    }
    {
        const float4* sv = reinterpret_cast<const float4*>(sSw);
        float4* o = reinterpret_cast<float4*>(out + SCALES_OFF + (size_t)waveBase * 3);
        nt_store4(sv[      lane], &o[      lane]);
        nt_store4(sv[ 64 + lane], &o[ 64 + lane]);
        nt_store4(sv[128 + lane], &o[128 + lane]);
    }
    {
        const float4* sv = reinterpret_cast<const float4*>(sHw);
        float4* o = reinterpret_cast<float4*>(out + HARM_OFF + (size_t)waveBase * 3);
        nt_store4(sv[      lane], &o[      lane]);
        nt_store4(sv[ 64 + lane], &o[ 64 + lane]);
        nt_store4(sv[128 + lane], &o[128 + lane]);
    }
}

extern "C" void kernel_launch(void* const* d_in, const int* in_sizes, int n_in,
                              void* d_out, int out_size, void* d_ws, size_t ws_size,
                              hipStream_t stream) {
    const float* ext    = (const float*)d_in[0];
    const float* intr   = (const float*)d_in[1];
    const float* depths = (const float*)d_in[2];
    const float* opac   = (const float*)d_in[3];
    const float* raw    = (const float*)d_in[4];
    float* out = (float*)d_out;

    ga_kernel<<<TOTc / 1024, 256, 0, stream>>>(ext, intr, depths, opac, raw, out);
}